// Round 5
// baseline (3913.925 us; speedup 1.0000x reference)
//
#include <hip/hip_runtime.h>

#define NN 200000
#define CC 64
#define EE 3200000

#define BINSHIFT 7
#define BINSZ 128
#define NBINS ((NN + BINSZ - 1) / BINSZ)     // 1563
#define SBLK 512
#define SITEMS 4
static_assert(NBINS <= SBLK * SITEMS, "scan capacity");

// ---------------- x -> bf16 (RNE) -----------------------------------------
__device__ __forceinline__ unsigned int bf16rne(float f) {
    unsigned int u = __float_as_uint(f);
    return (u + 0x7fffu + ((u >> 16) & 1u)) >> 16;
}

__global__ void __launch_bounds__(256) tobf16_kernel(
    const float* __restrict__ x, unsigned short* __restrict__ xh)
{
    int t = blockIdx.x * blockDim.x + threadIdx.x;
    if (t >= NN * CC / 8) return;
    const float4* x4 = (const float4*)x;
    float4 f0 = x4[2 * t], f1 = x4[2 * t + 1];
    int4 o;
    o.x = (int)(bf16rne(f0.x) | (bf16rne(f0.y) << 16));
    o.y = (int)(bf16rne(f0.z) | (bf16rne(f0.w) << 16));
    o.z = (int)(bf16rne(f1.x) | (bf16rne(f1.y) << 16));
    o.w = (int)(bf16rne(f1.z) | (bf16rne(f1.w) << 16));
    ((int4*)xh)[t] = o;
}

// ---------------- binning: count ------------------------------------------
__global__ void __launch_bounds__(256) bincount_kernel(
    const int* __restrict__ src, const int* __restrict__ dst,
    int* __restrict__ cnt1, int* __restrict__ cnt2)
{
    int e = blockIdx.x * blockDim.x + threadIdx.x;
    if (e >= EE) return;
    atomicAdd(&cnt1[dst[e] >> BINSHIFT], 1);
    atomicAdd(&cnt2[src[e] >> BINSHIFT], 1);
}

// ---------------- binning: exclusive scan over NBINS (single WG) ----------
__global__ void __launch_bounds__(SBLK) binscan_kernel(
    const int* __restrict__ cnt1, const int* __restrict__ cnt2,
    int* __restrict__ start1, int* __restrict__ cur1,
    int* __restrict__ start2, int* __restrict__ cur2)
{
    __shared__ int s[SBLK];
    int t = threadIdx.x;
    // --- dir1 ---
    {
        int d[SITEMS]; int sum = 0;
        #pragma unroll
        for (int k = 0; k < SITEMS; ++k) {
            int i = t * SITEMS + k;
            d[k] = (i < NBINS) ? cnt1[i] : 0;
            sum += d[k];
        }
        s[t] = sum; __syncthreads();
        for (int ofs = 1; ofs < SBLK; ofs <<= 1) {
            int nv = (t >= ofs) ? s[t - ofs] : 0; __syncthreads();
            s[t] += nv; __syncthreads();
        }
        int run = s[t] - sum;
        #pragma unroll
        for (int k = 0; k < SITEMS; ++k) {
            int i = t * SITEMS + k;
            if (i < NBINS) { start1[i] = run; cur1[i] = run; }
            run += d[k];
        }
    }
    __syncthreads();
    // --- dir2 ---
    {
        int d[SITEMS]; int sum = 0;
        #pragma unroll
        for (int k = 0; k < SITEMS; ++k) {
            int i = t * SITEMS + k;
            d[k] = (i < NBINS) ? cnt2[i] : 0;
            sum += d[k];
        }
        s[t] = sum; __syncthreads();
        for (int ofs = 1; ofs < SBLK; ofs <<= 1) {
            int nv = (t >= ofs) ? s[t - ofs] : 0; __syncthreads();
            s[t] += nv; __syncthreads();
        }
        int run = s[t] - sum;
        #pragma unroll
        for (int k = 0; k < SITEMS; ++k) {
            int i = t * SITEMS + k;
            if (i < NBINS) { start2[i] = run; cur2[i] = run; }
            run += d[k];
        }
    }
}

// ---------------- binning: fill (packed 4B payload appends) ---------------
__global__ void __launch_bounds__(256) binfill_kernel(
    const int* __restrict__ src, const int* __restrict__ dst,
    int* __restrict__ cur1, int* __restrict__ cur2,
    int* __restrict__ buf1, int* __restrict__ buf2)
{
    int e = blockIdx.x * blockDim.x + threadIdx.x;
    if (e >= EE) return;
    int s = src[e], t = dst[e];
    int p1 = atomicAdd(&cur1[t >> BINSHIFT], 1);
    buf1[p1] = ((t & (BINSZ - 1)) << 18) | s;     // row t-local += x[s]
    int p2 = atomicAdd(&cur2[s >> BINSHIFT], 1);
    buf2[p2] = ((s & (BINSZ - 1)) << 18) | t;     // row s-local += x[t]
}

// ---------------- accumulate one direction's bin edges into LDS -----------
__device__ __forceinline__ void accum_edges(
    const int* __restrict__ buf, int start, int count,
    const unsigned short* __restrict__ xh, float* lds, int lane, int wave)
{
    for (int blk = wave; blk * 64 < count; blk += 4) {
        int e0  = start + blk * 64;
        int rem = min(64, count - blk * 64);
        int payload = (lane < rem) ? buf[e0 + lane] : 0;
        int k = 0;
        for (; k + 8 <= rem; k += 8) {
            float f[8]; int ld[8];
            #pragma unroll
            for (int u = 0; u < 8; ++u) {
                int p = __shfl(payload, k + u, 64);
                ld[u] = p >> 18;
                int n = p & 0x3FFFF;
                f[u] = __uint_as_float((unsigned int)xh[(size_t)n * CC + lane] << 16);
            }
            #pragma unroll
            for (int u = 0; u < 8; ++u)
                atomicAdd(&lds[ld[u] * CC + lane], f[u]);
        }
        for (; k < rem; ++k) {
            int p = __shfl(payload, k, 64);
            int ldr = p >> 18;
            int n = p & 0x3FFFF;
            float f = __uint_as_float((unsigned int)xh[(size_t)n * CC + lane] << 16);
            atomicAdd(&lds[ldr * CC + lane], f);
        }
    }
}

// ---------------- fused bin-accumulate + scale + GEMM + relu + add --------
__global__ void __launch_bounds__(256) accum_gemm_kernel(
    const float* __restrict__ x, const unsigned short* __restrict__ xh,
    const int* __restrict__ buf1, const int* __restrict__ start1, const int* __restrict__ cnt1,
    const int* __restrict__ buf2, const int* __restrict__ start2, const int* __restrict__ cnt2,
    const float* __restrict__ norm, const float* __restrict__ norm_t,
    const float* __restrict__ Wo, const float* __restrict__ Wb,
    float* __restrict__ out)
{
    __shared__ float agg1[BINSZ * CC];   // 32 KB
    __shared__ float agg2[BINSZ * CC];   // 32 KB
    const int b    = blockIdx.x;
    const int base = b << BINSHIFT;
    const int tid  = threadIdx.x;
    const int lane = tid & 63;
    const int wave = tid >> 6;

    // init accumulators with the node's own fp32 row (identity term, exact)
    for (int idx = tid; idx < BINSZ * CC; idx += 256) {
        int r = idx >> 6, c = idx & 63;
        int i = base + r;
        float v = (i < NN) ? x[(size_t)i * CC + c] : 0.f;
        agg1[idx] = v;
        agg2[idx] = v;
    }
    __syncthreads();

    accum_edges(buf1, start1[b], cnt1[b], xh, agg1, lane, wave);
    accum_edges(buf2, start2[b], cnt2[b], xh, agg2, lane, wave);
    __syncthreads();

    // W rows in registers: lane j holds Wo[j][0..63], Wb[j][0..63]
    float wo[CC], wb[CC];
    {
        const float4* Wo4 = (const float4*)(Wo + (size_t)lane * CC);
        const float4* Wb4 = (const float4*)(Wb + (size_t)lane * CC);
        #pragma unroll
        for (int q = 0; q < CC / 4; ++q) {
            float4 a = Wo4[q];
            wo[4*q] = a.x; wo[4*q+1] = a.y; wo[4*q+2] = a.z; wo[4*q+3] = a.w;
            float4 c2 = Wb4[q];
            wb[4*q] = c2.x; wb[4*q+1] = c2.y; wb[4*q+2] = c2.z; wb[4*q+3] = c2.w;
        }
    }

    for (int r = wave; r < BINSZ; r += 4) {
        int i = base + r;
        if (i >= NN) break;
        float y1 = agg1[r * CC + lane] * norm[i];
        float y2 = agg2[r * CC + lane] * norm_t[i];
        float acc1 = 0.f, acc2 = 0.f;
        #pragma unroll
        for (int c = 0; c < CC; ++c) {
            acc1 = fmaf(__shfl(y1, c, 64), wo[c], acc1);
            acc2 = fmaf(__shfl(y2, c, 64), wb[c], acc2);
        }
        out[(size_t)i * CC + lane] = fmaxf(acc1, 0.f) + fmaxf(acc2, 0.f);
    }
}

// ---------------- fallback: direct atomic scatter (round-1 path) ----------
__global__ void __launch_bounds__(256) scatter2_kernel(
    const float* __restrict__ x, const int* __restrict__ src, const int* __restrict__ dst,
    float* __restrict__ agg1, float* __restrict__ agg2)
{
    int tid = blockIdx.x * blockDim.x + threadIdx.x;
    int e = tid >> 6, lane = tid & 63;
    if (e >= EE) return;
    int s = src[e], t = dst[e];
    atomicAdd(&agg1[(size_t)t * CC + lane], x[(size_t)s * CC + lane]);
    atomicAdd(&agg2[(size_t)s * CC + lane], x[(size_t)t * CC + lane]);
}

__global__ void __launch_bounds__(256) gemm2_kernel(
    const float* __restrict__ x, const float* __restrict__ agg1, const float* __restrict__ agg2,
    const float* __restrict__ norm, const float* __restrict__ norm_t,
    const float* __restrict__ Wo, const float* __restrict__ Wb, float* __restrict__ out)
{
    __shared__ float WoT[CC * CC];
    __shared__ float WbT[CC * CC];
    for (int idx = threadIdx.x; idx < CC * CC; idx += blockDim.x) {
        int j = idx >> 6, c = idx & 63;
        WoT[c * CC + j] = Wo[idx];
        WbT[c * CC + j] = Wb[idx];
    }
    __syncthreads();
    const int wave = threadIdx.x >> 6, lane = threadIdx.x & 63;
    const int wavesTotal = (gridDim.x * blockDim.x) >> 6;
    for (int i = blockIdx.x * (blockDim.x >> 6) + wave; i < NN; i += wavesTotal) {
        size_t base = (size_t)i * CC + lane;
        float y1 = norm[i]   * (x[base] + agg1[base]);
        float y2 = norm_t[i] * (x[base] + agg2[base]);
        float acc1 = 0.f, acc2 = 0.f;
        #pragma unroll
        for (int c = 0; c < CC; ++c) {
            acc1 = fmaf(__shfl(y1, c, 64), WoT[c * CC + lane], acc1);
            acc2 = fmaf(__shfl(y2, c, 64), WbT[c * CC + lane], acc2);
        }
        out[base] = fmaxf(acc1, 0.f) + fmaxf(acc2, 0.f);
    }
}

extern "C" void kernel_launch(void* const* d_in, const int* in_sizes, int n_in,
                              void* d_out, int out_size, void* d_ws, size_t ws_size,
                              hipStream_t stream) {
    const float* x      = (const float*)d_in[0];
    const int*   src    = (const int*)  d_in[1];
    const int*   dst    = (const int*)  d_in[2];
    const float* norm   = (const float*)d_in[3];
    const float* norm_t = (const float*)d_in[4];
    const float* W_out  = (const float*)d_in[5];
    const float* W_back = (const float*)d_in[6];
    float*       out    = (float*)d_out;

    const size_t xhBytes  = (size_t)NN * CC * 2;          // 25.6 MB
    const size_t bufBytes = (size_t)EE * 4;               // 12.8 MB each
    const size_t CPAD     = 2048;                          // counter array stride
    const size_t need = xhBytes + 2 * bufBytes + 6 * CPAD * sizeof(int);

    if (ws_size >= need) {
        char* p = (char*)d_ws;
        unsigned short* xh = (unsigned short*)p;  p += xhBytes;
        int* buf1   = (int*)p;  p += bufBytes;
        int* buf2   = (int*)p;  p += bufBytes;
        int* cnt1   = (int*)p;  p += CPAD * sizeof(int);
        int* cnt2   = (int*)p;  p += CPAD * sizeof(int);
        int* start1 = (int*)p;  p += CPAD * sizeof(int);
        int* cur1   = (int*)p;  p += CPAD * sizeof(int);
        int* start2 = (int*)p;  p += CPAD * sizeof(int);
        int* cur2   = (int*)p;  p += CPAD * sizeof(int);

        // zero all six counter arrays (cnt1..cur2 are contiguous)
        hipMemsetAsync(cnt1, 0, 6 * CPAD * sizeof(int), stream);
        tobf16_kernel<<<(NN * CC / 8 + 255) / 256, 256, 0, stream>>>(x, xh);
        bincount_kernel<<<(EE + 255) / 256, 256, 0, stream>>>(src, dst, cnt1, cnt2);
        binscan_kernel<<<1, SBLK, 0, stream>>>(cnt1, cnt2, start1, cur1, start2, cur2);
        binfill_kernel<<<(EE + 255) / 256, 256, 0, stream>>>(src, dst, cur1, cur2, buf1, buf2);
        accum_gemm_kernel<<<NBINS, 256, 0, stream>>>(x, xh,
                                                     buf1, start1, cnt1,
                                                     buf2, start2, cnt2,
                                                     norm, norm_t, W_out, W_back, out);
    } else {
        const size_t aggElems = (size_t)NN * CC;
        float* agg1 = (float*)d_ws;
        float* agg2 = agg1 + aggElems;
        hipMemsetAsync(d_ws, 0, 2 * aggElems * sizeof(float), stream);
        scatter2_kernel<<<(EE * 64) / 256, 256, 0, stream>>>(x, src, dst, agg1, agg2);
        gemm2_kernel<<<4096, 256, 0, stream>>>(x, agg1, agg2, norm, norm_t,
                                               W_out, W_back, out);
    }
}

// Round 6
// 3430.405 us; speedup vs baseline: 1.1410x; 1.1410x over previous
//
#include <hip/hip_runtime.h>

#define NN 200000
#define CC 64
#define EE 3200000

#define BINSHIFT 7
#define BINSZ 128
#define NBINS ((NN + BINSZ - 1) / BINSZ)     // 1563
#define CAP 3072                              // bin capacity (mean 2048, 22 sigma headroom)
#define CPAD 2048                             // counter array stride (>= NBINS)

// ---------------- x -> bf16 (RNE) -----------------------------------------
__device__ __forceinline__ unsigned int bf16rne(float f) {
    unsigned int u = __float_as_uint(f);
    return (u + 0x7fffu + ((u >> 16) & 1u)) >> 16;
}

__global__ void __launch_bounds__(256) tobf16_kernel(
    const float* __restrict__ x, unsigned short* __restrict__ xh)
{
    int t = blockIdx.x * blockDim.x + threadIdx.x;
    if (t >= NN * CC / 8) return;
    const float4* x4 = (const float4*)x;
    float4 f0 = x4[2 * t], f1 = x4[2 * t + 1];
    int4 o;
    o.x = (int)(bf16rne(f0.x) | (bf16rne(f0.y) << 16));
    o.y = (int)(bf16rne(f0.z) | (bf16rne(f0.w) << 16));
    o.z = (int)(bf16rne(f1.x) | (bf16rne(f1.y) << 16));
    o.w = (int)(bf16rne(f1.z) | (bf16rne(f1.w) << 16));
    ((int4*)xh)[t] = o;
}

// ---------------- single-pass binned append (fixed capacity) --------------
__global__ void __launch_bounds__(256) binfill_kernel(
    const int* __restrict__ src, const int* __restrict__ dst,
    int* __restrict__ cnt1, int* __restrict__ cnt2,
    int* __restrict__ buf1, int* __restrict__ buf2)
{
    int e = blockIdx.x * blockDim.x + threadIdx.x;
    if (e >= EE) return;
    int s = src[e], t = dst[e];
    int b1 = t >> BINSHIFT;
    int p1 = atomicAdd(&cnt1[b1], 1);
    if (p1 < CAP) buf1[(size_t)b1 * CAP + p1] = ((t & (BINSZ - 1)) << 18) | s;
    int b2 = s >> BINSHIFT;
    int p2 = atomicAdd(&cnt2[b2], 1);
    if (p2 < CAP) buf2[(size_t)b2 * CAP + p2] = ((s & (BINSZ - 1)) << 18) | t;
}

// ---------------- fused bin-accumulate + scale + GEMM + relu + add --------
// LDS slot swizzle: value of channel ch for local row r lives at
//   agg[r*64 + (ch ^ (r&7))]  -> ds_add banks ~2-way instead of 16-way.
__global__ void __launch_bounds__(512, 4) accum_gemm_kernel(
    const float* __restrict__ x, const int4* __restrict__ xh4,
    const int* __restrict__ buf1, const int* __restrict__ cnt1,
    const int* __restrict__ buf2, const int* __restrict__ cnt2,
    const float* __restrict__ norm, const float* __restrict__ norm_t,
    const float* __restrict__ Wo, const float* __restrict__ Wb,
    float* __restrict__ out)
{
    __shared__ float agg1[BINSZ * CC];   // 32 KB
    __shared__ float agg2[BINSZ * CC];   // 32 KB
    const int b    = blockIdx.x;
    const int base = b << BINSHIFT;
    const int tid  = threadIdx.x;
    const int lane = tid & 63;
    const int wave = tid >> 6;           // 0..7

    // init: own fp32 row (identity term, exact), swizzled slots
    for (int idx = tid; idx < BINSZ * CC; idx += 512) {
        int r = idx >> 6, ch = idx & 63;
        int i = base + r;
        float v = (i < NN) ? x[(size_t)i * CC + ch] : 0.f;
        int slot = r * CC + (ch ^ (r & 7));
        agg1[slot] = v;
        agg2[slot] = v;
    }
    __syncthreads();

    // gather+accumulate: waves 0-3 -> dir1, waves 4-7 -> dir2.
    // 8 lanes per row: group g = lane>>3 (row), sq = lane&7 (16B channel chunk).
    {
        const bool dir1  = (wave < 4);
        const int* ebuf  = (dir1 ? buf1 : buf2) + (size_t)b * CAP;
        const int  count = min(dir1 ? cnt1[b] : cnt2[b], CAP);
        float*     agg   = dir1 ? agg1 : agg2;
        const int  g  = lane >> 3;
        const int  sq = lane & 7;

        for (int c0 = (wave & 3) * 64; c0 < count; c0 += 256) {
            int rem = min(64, count - c0);
            int payload = (lane < rem) ? ebuf[c0 + lane] : 0;
            int4 u[8]; int rr[8];
            #pragma unroll
            for (int k = 0; k < 8; ++k) {
                int p = __shfl(payload, k * 8 + g, 64);
                rr[k] = p >> 18;
                bool act = (k * 8 + g) < rem;
                int4 t = act ? xh4[(size_t)(p & 0x3FFFF) * 8 + sq]
                             : make_int4(0, 0, 0, 0);   // adds 0.0f, harmless
                u[k] = t;
            }
            #pragma unroll
            for (int k = 0; k < 8; ++k) {
                int r7 = rr[k] & 7;
                float* p8 = agg + rr[k] * CC + 8 * sq;
                unsigned int w0 = (unsigned int)u[k].x, w1 = (unsigned int)u[k].y;
                unsigned int w2 = (unsigned int)u[k].z, w3 = (unsigned int)u[k].w;
                atomicAdd(p8 + (0 ^ r7), __uint_as_float(w0 << 16));
                atomicAdd(p8 + (1 ^ r7), __uint_as_float(w0 & 0xffff0000u));
                atomicAdd(p8 + (2 ^ r7), __uint_as_float(w1 << 16));
                atomicAdd(p8 + (3 ^ r7), __uint_as_float(w1 & 0xffff0000u));
                atomicAdd(p8 + (4 ^ r7), __uint_as_float(w2 << 16));
                atomicAdd(p8 + (5 ^ r7), __uint_as_float(w2 & 0xffff0000u));
                atomicAdd(p8 + (6 ^ r7), __uint_as_float(w3 << 16));
                atomicAdd(p8 + (7 ^ r7), __uint_as_float(w3 & 0xffff0000u));
            }
        }
    }
    __syncthreads();

    // GEMM: W rows in registers (lane j holds W[j][0..63])
    float wo[CC], wb[CC];
    {
        const float4* Wo4 = (const float4*)(Wo + (size_t)lane * CC);
        const float4* Wb4 = (const float4*)(Wb + (size_t)lane * CC);
        #pragma unroll
        for (int q = 0; q < CC / 4; ++q) {
            float4 a = Wo4[q];
            wo[4*q] = a.x; wo[4*q+1] = a.y; wo[4*q+2] = a.z; wo[4*q+3] = a.w;
            float4 c2 = Wb4[q];
            wb[4*q] = c2.x; wb[4*q+1] = c2.y; wb[4*q+2] = c2.z; wb[4*q+3] = c2.w;
        }
    }

    for (int r = wave; r < BINSZ; r += 8) {
        int i = base + r;
        if (i >= NN) break;
        int r7 = r & 7;
        float y1 = agg1[r * CC + (lane ^ r7)] * norm[i];
        float y2 = agg2[r * CC + (lane ^ r7)] * norm_t[i];
        float acc1 = 0.f, acc2 = 0.f;
        #pragma unroll
        for (int c = 0; c < CC; ++c) {
            acc1 = fmaf(__shfl(y1, c, 64), wo[c], acc1);
            acc2 = fmaf(__shfl(y2, c, 64), wb[c], acc2);
        }
        out[(size_t)i * CC + lane] = fmaxf(acc1, 0.f) + fmaxf(acc2, 0.f);
    }
}

// ---------------- fallback: direct atomic scatter (round-1 path) ----------
__global__ void __launch_bounds__(256) scatter2_kernel(
    const float* __restrict__ x, const int* __restrict__ src, const int* __restrict__ dst,
    float* __restrict__ agg1, float* __restrict__ agg2)
{
    int tid = blockIdx.x * blockDim.x + threadIdx.x;
    int e = tid >> 6, lane = tid & 63;
    if (e >= EE) return;
    int s = src[e], t = dst[e];
    atomicAdd(&agg1[(size_t)t * CC + lane], x[(size_t)s * CC + lane]);
    atomicAdd(&agg2[(size_t)s * CC + lane], x[(size_t)t * CC + lane]);
}

__global__ void __launch_bounds__(256) gemm2_kernel(
    const float* __restrict__ x, const float* __restrict__ agg1, const float* __restrict__ agg2,
    const float* __restrict__ norm, const float* __restrict__ norm_t,
    const float* __restrict__ Wo, const float* __restrict__ Wb, float* __restrict__ out)
{
    __shared__ float WoT[CC * CC];
    __shared__ float WbT[CC * CC];
    for (int idx = threadIdx.x; idx < CC * CC; idx += blockDim.x) {
        int j = idx >> 6, c = idx & 63;
        WoT[c * CC + j] = Wo[idx];
        WbT[c * CC + j] = Wb[idx];
    }
    __syncthreads();
    const int wave = threadIdx.x >> 6, lane = threadIdx.x & 63;
    const int wavesTotal = (gridDim.x * blockDim.x) >> 6;
    for (int i = blockIdx.x * (blockDim.x >> 6) + wave; i < NN; i += wavesTotal) {
        size_t base = (size_t)i * CC + lane;
        float y1 = norm[i]   * (x[base] + agg1[base]);
        float y2 = norm_t[i] * (x[base] + agg2[base]);
        float acc1 = 0.f, acc2 = 0.f;
        #pragma unroll
        for (int c = 0; c < CC; ++c) {
            acc1 = fmaf(__shfl(y1, c, 64), WoT[c * CC + lane], acc1);
            acc2 = fmaf(__shfl(y2, c, 64), WbT[c * CC + lane], acc2);
        }
        out[base] = fmaxf(acc1, 0.f) + fmaxf(acc2, 0.f);
    }
}

extern "C" void kernel_launch(void* const* d_in, const int* in_sizes, int n_in,
                              void* d_out, int out_size, void* d_ws, size_t ws_size,
                              hipStream_t stream) {
    const float* x      = (const float*)d_in[0];
    const int*   src    = (const int*)  d_in[1];
    const int*   dst    = (const int*)  d_in[2];
    const float* norm   = (const float*)d_in[3];
    const float* norm_t = (const float*)d_in[4];
    const float* W_out  = (const float*)d_in[5];
    const float* W_back = (const float*)d_in[6];
    float*       out    = (float*)d_out;

    const size_t xhBytes  = (size_t)NN * CC * 2;              // 25.6 MB
    const size_t bufBytes = (size_t)NBINS * CAP * 4;          // 19.2 MB each
    const size_t need = xhBytes + 2 * bufBytes + 2 * CPAD * sizeof(int);

    if (ws_size >= need) {
        char* p = (char*)d_ws;
        unsigned short* xh = (unsigned short*)p;  p += xhBytes;
        int* buf1 = (int*)p;  p += bufBytes;
        int* buf2 = (int*)p;  p += bufBytes;
        int* cnt1 = (int*)p;  p += CPAD * sizeof(int);
        int* cnt2 = (int*)p;  p += CPAD * sizeof(int);

        hipMemsetAsync(cnt1, 0, 2 * CPAD * sizeof(int), stream);
        tobf16_kernel<<<(NN * CC / 8 + 255) / 256, 256, 0, stream>>>(x, xh);
        binfill_kernel<<<(EE + 255) / 256, 256, 0, stream>>>(src, dst, cnt1, cnt2,
                                                             buf1, buf2);
        accum_gemm_kernel<<<NBINS, 512, 0, stream>>>(x, (const int4*)xh,
                                                     buf1, cnt1, buf2, cnt2,
                                                     norm, norm_t, W_out, W_back, out);
    } else {
        const size_t aggElems = (size_t)NN * CC;
        float* agg1 = (float*)d_ws;
        float* agg2 = agg1 + aggElems;
        hipMemsetAsync(d_ws, 0, 2 * aggElems * sizeof(float), stream);
        scatter2_kernel<<<(EE * 64) / 256, 256, 0, stream>>>(x, src, dst, agg1, agg2);
        gemm2_kernel<<<4096, 256, 0, stream>>>(x, agg1, agg2, norm, norm_t,
                                               W_out, W_back, out);
    }
}

// Round 7
// 3392.605 us; speedup vs baseline: 1.1537x; 1.0111x over previous
//
#include <hip/hip_runtime.h>

#define NN 200000
#define CC 64
#define EE 3200000

#define BINSHIFT 7
#define BINSZ 128
#define NBINS ((NN + BINSZ - 1) / BINSZ)     // 1563
#define CAP 3072                              // bin capacity (mean 2048, 22 sigma headroom)
#define CPAD 2048                             // counter array stride (>= NBINS)

// ---------------- x -> bf16 (RNE) -----------------------------------------
__device__ __forceinline__ unsigned int bf16rne(float f) {
    unsigned int u = __float_as_uint(f);
    return (u + 0x7fffu + ((u >> 16) & 1u)) >> 16;
}

__global__ void __launch_bounds__(256) tobf16_kernel(
    const float* __restrict__ x, unsigned short* __restrict__ xh)
{
    int t = blockIdx.x * blockDim.x + threadIdx.x;
    if (t >= NN * CC / 8) return;
    const float4* x4 = (const float4*)x;
    float4 f0 = x4[2 * t], f1 = x4[2 * t + 1];
    int4 o;
    o.x = (int)(bf16rne(f0.x) | (bf16rne(f0.y) << 16));
    o.y = (int)(bf16rne(f0.z) | (bf16rne(f0.w) << 16));
    o.z = (int)(bf16rne(f1.x) | (bf16rne(f1.y) << 16));
    o.w = (int)(bf16rne(f1.z) | (bf16rne(f1.w) << 16));
    ((int4*)xh)[t] = o;
}

// ---------------- single-pass binned append (fixed capacity) --------------
__global__ void __launch_bounds__(256) binfill_kernel(
    const int* __restrict__ src, const int* __restrict__ dst,
    int* __restrict__ cnt1, int* __restrict__ cnt2,
    int* __restrict__ buf1, int* __restrict__ buf2)
{
    int e = blockIdx.x * blockDim.x + threadIdx.x;
    if (e >= EE) return;
    int s = src[e], t = dst[e];
    int b1 = t >> BINSHIFT;
    int p1 = atomicAdd(&cnt1[b1], 1);
    if (p1 < CAP) buf1[(size_t)b1 * CAP + p1] = ((t & (BINSZ - 1)) << 18) | s;
    int b2 = s >> BINSHIFT;
    int p2 = atomicAdd(&cnt2[b2], 1);
    if (p2 < CAP) buf2[(size_t)b2 * CAP + p2] = ((s & (BINSZ - 1)) << 18) | t;
}

// ---------------- fused bin-accumulate + scale + GEMM + relu + add --------
// LDS slot swizzle: channel ch of local row r lives at agg[r*64 + (ch^(r&7))]
// -> ds_add spreads over ~32 banks (2-way, free).
// ACCUM names the __shared__ array LITERALLY so the compiler proves LDS
// address space and emits ds_add_f32 (NOT flat atomics — round-5/6 bug).
#define LDS_ADD(PTR, VAL) \
    (void)__hip_atomic_fetch_add((PTR), (VAL), __ATOMIC_RELAXED, \
                                 __HIP_MEMORY_SCOPE_WORKGROUP)

#define ACCUM(EBUF, COUNT, AGG)                                               \
    for (int c0 = (wave & 3) * 64; c0 < (COUNT); c0 += 256) {                 \
        int rem = min(64, (COUNT) - c0);                                      \
        int payload = (lane < rem) ? (EBUF)[c0 + lane] : 0;                   \
        int4 u[8]; int rr[8];                                                 \
        _Pragma("unroll")                                                     \
        for (int k = 0; k < 8; ++k) {                                         \
            int p = __shfl(payload, k * 8 + g, 64);                           \
            rr[k] = p >> 18;                                                  \
            bool act = (k * 8 + g) < rem;                                     \
            u[k] = act ? xh4[(size_t)(p & 0x3FFFF) * 8 + sq]                  \
                       : make_int4(0, 0, 0, 0);                               \
        }                                                                     \
        _Pragma("unroll")                                                     \
        for (int k = 0; k < 8; ++k) {                                         \
            int r7 = rr[k] & 7;                                               \
            int s8 = rr[k] * CC + 8 * sq;                                     \
            unsigned int w0 = (unsigned int)u[k].x, w1 = (unsigned int)u[k].y;\
            unsigned int w2 = (unsigned int)u[k].z, w3 = (unsigned int)u[k].w;\
            LDS_ADD(&AGG[s8 + (0 ^ r7)], __uint_as_float(w0 << 16));          \
            LDS_ADD(&AGG[s8 + (1 ^ r7)], __uint_as_float(w0 & 0xffff0000u));  \
            LDS_ADD(&AGG[s8 + (2 ^ r7)], __uint_as_float(w1 << 16));          \
            LDS_ADD(&AGG[s8 + (3 ^ r7)], __uint_as_float(w1 & 0xffff0000u));  \
            LDS_ADD(&AGG[s8 + (4 ^ r7)], __uint_as_float(w2 << 16));          \
            LDS_ADD(&AGG[s8 + (5 ^ r7)], __uint_as_float(w2 & 0xffff0000u));  \
            LDS_ADD(&AGG[s8 + (6 ^ r7)], __uint_as_float(w3 << 16));          \
            LDS_ADD(&AGG[s8 + (7 ^ r7)], __uint_as_float(w3 & 0xffff0000u));  \
        }                                                                     \
    }

__global__ void __launch_bounds__(512, 4) accum_gemm_kernel(
    const float* __restrict__ x, const int4* __restrict__ xh4,
    const int* __restrict__ buf1, const int* __restrict__ cnt1,
    const int* __restrict__ buf2, const int* __restrict__ cnt2,
    const float* __restrict__ norm, const float* __restrict__ norm_t,
    const float* __restrict__ Wo, const float* __restrict__ Wb,
    float* __restrict__ out)
{
    __shared__ float agg1[BINSZ * CC];   // 32 KB
    __shared__ float agg2[BINSZ * CC];   // 32 KB
    const int b    = blockIdx.x;
    const int base = b << BINSHIFT;
    const int tid  = threadIdx.x;
    const int lane = tid & 63;
    const int wave = tid >> 6;           // 0..7

    // init: own fp32 row (identity term, exact), swizzled slots
    for (int idx = tid; idx < BINSZ * CC; idx += 512) {
        int r = idx >> 6, ch = idx & 63;
        int i = base + r;
        float v = (i < NN) ? x[(size_t)i * CC + ch] : 0.f;
        int slot = r * CC + (ch ^ (r & 7));
        agg1[slot] = v;
        agg2[slot] = v;
    }
    __syncthreads();

    // gather+accumulate: waves 0-3 -> dir1, waves 4-7 -> dir2.
    // 8 lanes per row: g = lane>>3 (row group), sq = lane&7 (16B chunk).
    {
        const int g  = lane >> 3;
        const int sq = lane & 7;
        if (wave < 4) {
            const int* eb = buf1 + (size_t)b * CAP;
            const int  cn = min(cnt1[b], CAP);
            ACCUM(eb, cn, agg1)
        } else {
            const int* eb = buf2 + (size_t)b * CAP;
            const int  cn = min(cnt2[b], CAP);
            ACCUM(eb, cn, agg2)
        }
    }
    __syncthreads();

    // GEMM: W rows in registers (lane j holds W[j][0..63])
    float wo[CC], wb[CC];
    {
        const float4* Wo4 = (const float4*)(Wo + (size_t)lane * CC);
        const float4* Wb4 = (const float4*)(Wb + (size_t)lane * CC);
        #pragma unroll
        for (int q = 0; q < CC / 4; ++q) {
            float4 a = Wo4[q];
            wo[4*q] = a.x; wo[4*q+1] = a.y; wo[4*q+2] = a.z; wo[4*q+3] = a.w;
            float4 c2 = Wb4[q];
            wb[4*q] = c2.x; wb[4*q+1] = c2.y; wb[4*q+2] = c2.z; wb[4*q+3] = c2.w;
        }
    }

    for (int r = wave; r < BINSZ; r += 8) {
        int i = base + r;
        if (i >= NN) break;
        int r7 = r & 7;
        float y1 = agg1[r * CC + (lane ^ r7)] * norm[i];
        float y2 = agg2[r * CC + (lane ^ r7)] * norm_t[i];
        float acc1 = 0.f, acc2 = 0.f;
        #pragma unroll
        for (int c = 0; c < CC; ++c) {
            acc1 = fmaf(__shfl(y1, c, 64), wo[c], acc1);
            acc2 = fmaf(__shfl(y2, c, 64), wb[c], acc2);
        }
        out[(size_t)i * CC + lane] = fmaxf(acc1, 0.f) + fmaxf(acc2, 0.f);
    }
}

// ---------------- fallback: direct atomic scatter (round-1 path) ----------
__global__ void __launch_bounds__(256) scatter2_kernel(
    const float* __restrict__ x, const int* __restrict__ src, const int* __restrict__ dst,
    float* __restrict__ agg1, float* __restrict__ agg2)
{
    int tid = blockIdx.x * blockDim.x + threadIdx.x;
    int e = tid >> 6, lane = tid & 63;
    if (e >= EE) return;
    int s = src[e], t = dst[e];
    atomicAdd(&agg1[(size_t)t * CC + lane], x[(size_t)s * CC + lane]);
    atomicAdd(&agg2[(size_t)s * CC + lane], x[(size_t)t * CC + lane]);
}

__global__ void __launch_bounds__(256) gemm2_kernel(
    const float* __restrict__ x, const float* __restrict__ agg1, const float* __restrict__ agg2,
    const float* __restrict__ norm, const float* __restrict__ norm_t,
    const float* __restrict__ Wo, const float* __restrict__ Wb, float* __restrict__ out)
{
    __shared__ float WoT[CC * CC];
    __shared__ float WbT[CC * CC];
    for (int idx = threadIdx.x; idx < CC * CC; idx += blockDim.x) {
        int j = idx >> 6, c = idx & 63;
        WoT[c * CC + j] = Wo[idx];
        WbT[c * CC + j] = Wb[idx];
    }
    __syncthreads();
    const int wave = threadIdx.x >> 6, lane = threadIdx.x & 63;
    const int wavesTotal = (gridDim.x * blockDim.x) >> 6;
    for (int i = blockIdx.x * (blockDim.x >> 6) + wave; i < NN; i += wavesTotal) {
        size_t base = (size_t)i * CC + lane;
        float y1 = norm[i]   * (x[base] + agg1[base]);
        float y2 = norm_t[i] * (x[base] + agg2[base]);
        float acc1 = 0.f, acc2 = 0.f;
        #pragma unroll
        for (int c = 0; c < CC; ++c) {
            acc1 = fmaf(__shfl(y1, c, 64), WoT[c * CC + lane], acc1);
            acc2 = fmaf(__shfl(y2, c, 64), WbT[c * CC + lane], acc2);
        }
        out[base] = fmaxf(acc1, 0.f) + fmaxf(acc2, 0.f);
    }
}

extern "C" void kernel_launch(void* const* d_in, const int* in_sizes, int n_in,
                              void* d_out, int out_size, void* d_ws, size_t ws_size,
                              hipStream_t stream) {
    const float* x      = (const float*)d_in[0];
    const int*   src    = (const int*)  d_in[1];
    const int*   dst    = (const int*)  d_in[2];
    const float* norm   = (const float*)d_in[3];
    const float* norm_t = (const float*)d_in[4];
    const float* W_out  = (const float*)d_in[5];
    const float* W_back = (const float*)d_in[6];
    float*       out    = (float*)d_out;

    const size_t xhBytes  = (size_t)NN * CC * 2;              // 25.6 MB
    const size_t bufBytes = (size_t)NBINS * CAP * 4;          // 19.2 MB each
    const size_t need = xhBytes + 2 * bufBytes + 2 * CPAD * sizeof(int);

    if (ws_size >= need) {
        char* p = (char*)d_ws;
        unsigned short* xh = (unsigned short*)p;  p += xhBytes;
        int* buf1 = (int*)p;  p += bufBytes;
        int* buf2 = (int*)p;  p += bufBytes;
        int* cnt1 = (int*)p;  p += CPAD * sizeof(int);
        int* cnt2 = (int*)p;  p += CPAD * sizeof(int);

        hipMemsetAsync(cnt1, 0, 2 * CPAD * sizeof(int), stream);
        tobf16_kernel<<<(NN * CC / 8 + 255) / 256, 256, 0, stream>>>(x, xh);
        binfill_kernel<<<(EE + 255) / 256, 256, 0, stream>>>(src, dst, cnt1, cnt2,
                                                             buf1, buf2);
        accum_gemm_kernel<<<NBINS, 512, 0, stream>>>(x, (const int4*)xh,
                                                     buf1, cnt1, buf2, cnt2,
                                                     norm, norm_t, W_out, W_back, out);
    } else {
        const size_t aggElems = (size_t)NN * CC;
        float* agg1 = (float*)d_ws;
        float* agg2 = agg1 + aggElems;
        hipMemsetAsync(d_ws, 0, 2 * aggElems * sizeof(float), stream);
        scatter2_kernel<<<(EE * 64) / 256, 256, 0, stream>>>(x, src, dst, agg1, agg2);
        gemm2_kernel<<<4096, 256, 0, stream>>>(x, agg1, agg2, norm, norm_t,
                                               W_out, W_back, out);
    }
}